// Round 6
// baseline (1767.856 us; speedup 1.0000x reference)
//
#include <hip/hip_runtime.h>
#include <math.h>

#define NB   256
#define ND   63
#define NN   3969        // 63*63
#define MIDc 32

__device__ __forceinline__ float gelu_f(float v){
    return 0.5f * v * (1.0f + erff(v * 0.70710678118654752440f));
}

#define FMA4(A, W, S) { (A).x=fmaf((W).x,(S),(A).x); (A).y=fmaf((W).y,(S),(A).y); \
                        (A).z=fmaf((W).z,(S),(A).z); (A).w=fmaf((W).w,(S),(A).w); }

union F4 { float4 v; float a[4]; };
union W16 { float4 v[4]; float a[16]; };

// ---------------- DFT tables (64x64, row/col 63 zeroed) + acc reset ----------
__global__ void k_tables(float* __restrict__ Fr, float* __restrict__ Fi, float* __restrict__ acc){
    int idx = blockIdx.x * blockDim.x + threadIdx.x;
    if (idx < 4096){
        int r = idx >> 6, c = idx & 63;
        float vr = 0.f, vi = 0.f;
        if (r < 63 && c < 63){
            int m = (r * c) % 63;
            float ang = 6.283185307179586f * (float)m / 63.0f;
            vr = cosf(ang); vi = -sinf(ang);
        }
        Fr[idx] = vr; Fi[idx] = vi;
    }
    if (idx == 0) acc[0] = 0.f;
}

// -------- weight prep ---------------------------------------------------------
__global__ void k_wprep(const float* __restrict__ w1, const float* __restrict__ w2,
                        const float* __restrict__ w3, const float* __restrict__ w4,
                        const float* __restrict__ w5,
                        float* __restrict__ o1, float* __restrict__ o2,
                        float* __restrict__ o3, float* __restrict__ o4,
                        float* __restrict__ o5){
    int idx = blockIdx.x * blockDim.x + threadIdx.x;
    if (idx < 9216){
        int co = idx & 31, t = idx >> 5;
        int ci = t & 31, tap = t >> 5;
        int ky = tap / 3, kx = tap % 3;
        int src = ((ci*32 + co)*3 + ky)*3 + kx;
        o2[idx] = w2[src]; o3[idx] = w3[src]; o4[idx] = w4[src];
    }
    if (idx < 576){
        int co = idx & 1, t = idx >> 1;
        int ci = t & 31, tap = t >> 5;
        int ky = tap / 3, kx = tap % 3;
        o5[idx] = w5[((ci*2 + co)*3 + ky)*3 + kx];
    }
    if (idx < 288){
        int co = idx & 31, tap = idx >> 5;
        int ky = tap / 3, kx = tap % 3;
        o1[idx] = w1[(co*3 + ky)*3 + kx];
    }
}

// ---------------- hypernet ----------------------------------------------------
__global__ void k_hyper(const float* __restrict__ kA,
                        const float* __restrict__ w1a, const float* __restrict__ b1a,
                        const float* __restrict__ w2a, const float* __restrict__ b2a,
                        const float* __restrict__ w1b, const float* __restrict__ b1b,
                        const float* __restrict__ w2b, const float* __restrict__ b2b,
                        float* __restrict__ out1, float* __restrict__ out2){
    __shared__ float a[9];
    __shared__ float hid[100];
    int b = blockIdx.x, tid = threadIdx.x;
    if (tid < 9) a[tid] = kA[b*9 + tid];
    __syncthreads();
    if (tid < 100){
        float s = b1a[tid];
        #pragma unroll
        for (int i = 0; i < 9; i++) s = fmaf(a[i], w1a[i*100 + tid], s);
        hid[tid] = gelu_f(s);
    }
    __syncthreads();
    if (tid < 147){
        float s = b2a[tid];
        for (int k = 0; k < 100; k++) s = fmaf(hid[k], w2a[k*147 + tid], s);
        out1[b*147 + tid] = s;
    }
    __syncthreads();
    if (tid < 100){
        float s = b1b[tid];
        #pragma unroll
        for (int i = 0; i < 9; i++) s = fmaf(a[i], w1b[i*100 + tid], s);
        hid[tid] = gelu_f(s);
    }
    __syncthreads();
    if (tid < 147){
        float s = b2b[tid];
        for (int k = 0; k < 100; k++) s = fmaf(hid[k], w2b[k*147 + tid], s);
        out2[b*147 + tid] = s;
    }
}

// ---------------- ct1: 1->32, channel-last out --------------------------------
__global__ void k_ct1c(const float* __restrict__ kA, const float* __restrict__ wT1,
                       const float* __restrict__ bias, float* __restrict__ out){
    int idx = blockIdx.x * blockDim.x + threadIdx.x;
    if (idx >= NB*25) return;
    int p = idx % 25, b = idx / 25;
    int oy = p / 5, ox = p % 5;
    F4 acc[8];
    #pragma unroll
    for (int q = 0; q < 8; q++) acc[q].v = ((const float4*)bias)[q];
    int nky, kyA[2], iyA[2];
    if (oy & 1){ nky=2; kyA[0]=0; iyA[0]=(oy+1)/2; kyA[1]=2; iyA[1]=(oy-1)/2; }
    else       { nky=1; kyA[0]=1; iyA[0]=oy/2; kyA[1]=1; iyA[1]=0; }
    int nkx, kxA[2], ixA[2];
    if (ox & 1){ nkx=2; kxA[0]=0; ixA[0]=(ox+1)/2; kxA[1]=2; ixA[1]=(ox-1)/2; }
    else       { nkx=1; kxA[0]=1; ixA[0]=ox/2; kxA[1]=1; ixA[1]=0; }
    const float* ab = kA + b*9;
    for (int yi = 0; yi < nky; yi++)
    for (int xi = 0; xi < nkx; xi++){
        float v = ab[iyA[yi]*3 + ixA[xi]];
        const float4* wq = (const float4*)(wT1 + (kyA[yi]*3 + kxA[xi])*32);
        #pragma unroll
        for (int q = 0; q < 8; q++){ float4 w = wq[q]; FMA4(acc[q].v, w, v); }
    }
    float* ob = out + (size_t)idx*32;
    #pragma unroll
    for (int q = 0; q < 8; q++){
        float4 g; g.x=gelu_f(acc[q].a[0]); g.y=gelu_f(acc[q].a[1]);
        g.z=gelu_f(acc[q].a[2]); g.w=gelu_f(acc[q].a[3]);
        ((float4*)ob)[q] = g;
    }
}

// ------------- ct 32->32, stride2 pad1 k3, gelu, channel-last. 2 blocks/sample.
template<int HIN>
__global__ __launch_bounds__(512, 4) void k_ct32c(const float* __restrict__ in,
                                                  const float* __restrict__ wT,
                                                  const float* __restrict__ bias,
                                                  float* __restrict__ out){
    constexpr int HOUT = 2*HIN - 1;
    constexpr int HINP = (HIN + 3) & ~3;
    constexpr int OCT  = (HOUT + 7) / 8;
    constexpr int UPR  = OCT * 4;
    constexpr int NODD = (HOUT/2) * UPR;
    constexpr int TOT  = HOUT * UPR;
    constexpr int HT   = (TOT + 1) / 2;
    constexpr int INEL = 32*HIN*HINP;
    __shared__ __align__(16) float lds[INEL + 9216 + 32];
    float* in_s   = lds;
    float* w_s    = lds + INEL;
    float* bias_s = lds + INEL + 9216;
    const int b = blockIdx.x >> 1, h = blockIdx.x & 1;
    const int tid = threadIdx.x;
    { const float4* src = (const float4*)wT; float4* dst = (float4*)w_s;
      for (int i = tid; i < 2304; i += 512) dst[i] = src[i]; }
    if (tid < 32) bias_s[tid] = bias[tid];
    { const float* gi = in + (size_t)b * (32*HIN*HIN);
      for (int i = tid; i < 32*HIN*HIN; i += 512){
        int ci = i & 31, px = i >> 5;
        int y = px / HIN, x = px % HIN;
        in_s[ci*(HIN*HINP) + y*HINP + x] = gi[i];
      } }
    __syncthreads();
    float* ob0 = out + (size_t)b*(HOUT*HOUT*32);
    const int u0 = h*HT, u1 = (u0 + HT < TOT) ? (u0 + HT) : TOT;
    for (int u = u0 + tid; u < u1; u += 512){
        int r, s;
        if (u < NODD){ r = 2*(u/UPR) + 1; s = u % UPR; }
        else { int v = u - NODD; r = 2*(v/UPR); s = v % UPR; }
        const int m = s >> 2, cog = s & 3;
        const int x4 = 4*m;
        F4 acc[8][2];
        { float4 b0 = ((const float4*)bias_s)[cog*2];
          float4 b1 = ((const float4*)bias_s)[cog*2+1];
          #pragma unroll
          for (int p = 0; p < 8; p++){ acc[p][0].v = b0; acc[p][1].v = b1; } }
        int nky, kyA[2], iyA[2];
        if (r & 1){ int rI = r >> 1; nky = 2; kyA[0]=0; iyA[0]=rI+1; kyA[1]=2; iyA[1]=rI; }
        else      { nky = 1; kyA[0]=1; iyA[0]= r >> 1; kyA[1]=1; iyA[1]=0; }
        for (int yi = 0; yi < nky; yi++){
            const float* ip = in_s + iyA[yi]*HINP + x4;
            const float* wp = w_s + kyA[yi]*3*1024 + cog*8;
            #pragma unroll 2
            for (int ci = 0; ci < 32; ci++){
                F4 iv0, iv1;
                iv0.v = *(const float4*)(ip);
                iv1.v = *(const float4*)(ip + 4);
                float4 w0a = *(const float4*)(wp);
                float4 w0b = *(const float4*)(wp + 4);
                float4 w1a = *(const float4*)(wp + 1024);
                float4 w1b = *(const float4*)(wp + 1028);
                float4 w2a = *(const float4*)(wp + 2048);
                float4 w2b = *(const float4*)(wp + 2052);
                #pragma unroll
                for (int p = 0; p < 4; p++){
                    float ev = iv0.a[p];
                    FMA4(acc[2*p][0].v, w1a, ev);
                    FMA4(acc[2*p][1].v, w1b, ev);
                    float o0 = (p < 3) ? iv0.a[p+1] : iv1.a[0];
                    FMA4(acc[2*p+1][0].v, w0a, o0);
                    FMA4(acc[2*p+1][1].v, w0b, o0);
                    FMA4(acc[2*p+1][0].v, w2a, ev);
                    FMA4(acc[2*p+1][1].v, w2b, ev);
                }
                ip += HIN*HINP;
                wp += 32;
            }
        }
        int lim = HOUT - 8*m; if (lim > 8) lim = 8;
        float* ob = ob0 + ((size_t)r*HOUT + 8*m)*32 + cog*8;
        for (int e = 0; e < lim; e++){
            float4 g0, g1;
            g0.x=gelu_f(acc[e][0].a[0]); g0.y=gelu_f(acc[e][0].a[1]);
            g0.z=gelu_f(acc[e][0].a[2]); g0.w=gelu_f(acc[e][0].a[3]);
            g1.x=gelu_f(acc[e][1].a[0]); g1.y=gelu_f(acc[e][1].a[1]);
            g1.z=gelu_f(acc[e][1].a[2]); g1.w=gelu_f(acc[e][1].a[3]);
            *(float4*)(ob + (size_t)e*32)     = g0;
            *(float4*)(ob + (size_t)e*32 + 4) = g1;
        }
    }
}

// ---- ct5 (32->2) + build v rows 0..31 (interleaved) + dv --------------------
__global__ __launch_bounds__(512) void k_ct5v(const float* __restrict__ in,
                                              const float* __restrict__ wT5,
                                              const float* __restrict__ bias,
                                              float* __restrict__ vcg,
                                              float* __restrict__ dvg){
    __shared__ float ws5[576];
    __shared__ float c5s[2*NN];
    const int b = blockIdx.x, tid = threadIdx.x;
    for (int i = tid; i < 576; i += 512) ws5[i] = wT5[i];
    __syncthreads();
    const float* ib = in + (size_t)b * (32*33*33);
    float b0 = bias[0], b1 = bias[1];
    for (int p = tid; p < NN; p += 512){
        int oy = p / ND, ox = p % ND;
        float a0 = b0, a1 = b1;
        int nky, kyA[2], iyA[2];
        if ((oy & 1) == 0){ nky=2; kyA[0]=0; iyA[0]=oy/2+1; kyA[1]=2; iyA[1]=oy/2; }
        else              { nky=1; kyA[0]=1; iyA[0]=(oy+1)/2; kyA[1]=1; iyA[1]=0; }
        int nkx, kxA[2], ixA[2];
        if ((ox & 1) == 0){ nkx=2; kxA[0]=0; ixA[0]=ox/2+1; kxA[1]=2; ixA[1]=ox/2; }
        else              { nkx=1; kxA[0]=1; ixA[0]=(ox+1)/2; kxA[1]=1; ixA[1]=0; }
        for (int yi = 0; yi < nky; yi++)
        for (int xi = 0; xi < nkx; xi++){
            const float* ip = ib + ((size_t)iyA[yi]*33 + ixA[xi])*32;
            const float* wp = ws5 + (kyA[yi]*3 + kxA[xi])*64;
            #pragma unroll
            for (int g = 0; g < 8; g++){
                F4 iv; iv.v = *(const float4*)(ip + 4*g);
                #pragma unroll
                for (int q = 0; q < 4; q++){
                    int ci = 4*g + q;
                    a0 = fmaf(iv.a[q], wp[ci*2],   a0);
                    a1 = fmaf(iv.a[q], wp[ci*2+1], a1);
                }
            }
        }
        c5s[p]      = a0;
        c5s[NN + p] = a1;
    }
    __syncthreads();
    const float sc = 1.0f / 3969.0f;
    float4* vc4 = (float4*)vcg;
    for (int i = tid; i < 1024; i += 512){
        int ky = i >> 5, ct2 = i & 31;
        float4 o;
        #pragma unroll
        for (int j = 0; j < 2; j++){
            int kx = 2*ct2 + j;
            float re = 0.f, im = 0.f;
            if (kx <= 31){ int o2 = 2*(ky*ND + kx); re = c5s[o2]*sc; im = c5s[o2+1]*sc; }
            else if (kx <= 62){
                int sy = (ND - ky) % ND, sx = ND - kx;
                int o2 = 2*(sy*ND + sx); re = c5s[o2]*sc; im = -c5s[o2+1]*sc;
            }
            if (j == 0){ o.x = re; o.y = im; } else { o.z = re; o.w = im; }
        }
        vc4[(size_t)b*1024 + i] = o;
    }
    if (tid < 32){
        float2* dv2 = (float2*)dvg;
        float2 d = {0.f, 0.f};
        if (tid >= 1){
            int iA = (ND - tid) * ND, iB = tid * ND;
            d.x = (c5s[2*iA]     - c5s[2*iB])     * sc;
            d.y = (c5s[2*iA + 1] + c5s[2*iB + 1]) * sc;
        }
        dv2[b*32 + tid] = d;
    }
}

// ---------------- mega solver, 1024 threads, Hermitian-halved DFT ------------
__global__ __launch_bounds__(1024, 4) void k_solve(const float* __restrict__ x0g,
                                                   const float* __restrict__ f,
                                                   const float* __restrict__ kAg,
                                                   const float* __restrict__ w1g,
                                                   const float* __restrict__ w2g,
                                                   const float* __restrict__ Frg,
                                                   const float* __restrict__ Fig,
                                                   const float* __restrict__ vcg,
                                                   const float* __restrict__ dvg,
                                                   float* __restrict__ accg){
    __shared__ __align__(16) float xs[63*68 + 4];    // stride 68, cols 63.. pad
    __shared__ __align__(16) float U[8576];          // union: rs+tc | rP,TtC,MC,CC
    __shared__ float w1s[148], w2s[148], dvs[64], ds_r[32], ds_i[32], red[16];
    const int b = blockIdx.x, tid = threadIdx.x;
    float* rs = U;                       // 63*68
    float* tc = U + 4284;                // 63*68 (rs right-halo aliases tc[0..1]=0)
    float*  rP  = U;                     // 64x64
    float2* TtC = (float2*)(U + 4096);   // 64 x 32 f2, swizzled cols
    float2* MC2 = (float2*)U;            // 32 x 64 f2
    float4* MC4 = (float4*)U;
    float4* CC4 = (float4*)(U + 4096);   // 32 x 33 f4 (66 f2 stride)
    float2* rP2 = (float2*)U;
    const float* fg = f + (size_t)b*NN;
    float ka[9];
    #pragma unroll
    for (int i = 0; i < 9; i++) ka[i] = kAg[b*9 + i];
    if (tid < 147){ w1s[tid] = w1g[b*147 + tid]; w2s[tid] = w2g[b*147 + tid]; }
    if (tid < 64) dvs[tid] = dvg[b*64 + tid];
    for (int i = tid; i < NN; i += 1024) xs[(i/ND)*68 + (i%ND)] = x0g[(size_t)b*NN + i];
    __syncthreads();

    const int kt5 = tid >> 5, ct2 = tid & 31;      // DFT A/B/D tiling
    const int pE  = tid >> 4, ctE = tid & 15;      // phase E tiling

    for (int it = 0; it < 5; it++){
        // ---- zero union (smoother halos) ----
        { float4 z = {0.f,0.f,0.f,0.f}; float4* U4 = (float4*)U;
          for (int i = tid; i < 2144; i += 1024) U4[i] = z; }
        __syncthreads();
        // ---- residual -> rs (col c at idx c+4) ----
        for (int i = tid; i < NN; i += 1024){
            int y = i / ND, xx = i % ND;
            float s = 0.f;
            #pragma unroll
            for (int dy = 0; dy < 3; dy++){
                int u = y + dy;
                #pragma unroll
                for (int dx = 0; dx < 3; dx++){
                    int v = xx + dx;
                    float p;
                    if (u == 64 || v == 64)    p = 1.0f;
                    else if (u == 0 || v == 0) p = 0.0f;
                    else                       p = xs[(u-1)*68 + (v-1)];
                    s = fmaf(p, ka[dy*3 + dx], s);
                }
            }
            rs[y*68 + 4 + xx] = fg[i] - s;
        }
        __syncthreads();
        // ---- smoother: 2-row x 8-px units, 256 active lanes ----
        const bool act = tid < 256;
        const int rg = tid >> 3, x0c = 8*(tid & 7);
        const int r0 = 2*rg;
        float acc2[2][8] = {};
        for (int c = 0; c < 3; c++){
            if (act){
                float a1[2][8] = {};
                #pragma unroll
                for (int wy = 0; wy < 8; wy++){
                    int ry = r0 - 3 + wy;
                    W16 w; w.v[0]=w.v[1]=w.v[2]=w.v[3] = make_float4(0.f,0.f,0.f,0.f);
                    if (ry >= 0 && ry <= 62){
                        const float4* rp = (const float4*)(rs + ry*68 + x0c);
                        w.v[0]=rp[0]; w.v[1]=rp[1]; w.v[2]=rp[2]; w.v[3]=rp[3];
                    }
                    if (wy <= 6){
                        #pragma unroll
                        for (int dx = 0; dx < 7; dx++){
                            float wv = w1s[c*49 + wy*7 + dx];
                            #pragma unroll
                            for (int t = 0; t < 8; t++) a1[0][t] = fmaf(wv, w.a[t+dx+1], a1[0][t]);
                        }
                    }
                    if (wy >= 1){
                        #pragma unroll
                        for (int dx = 0; dx < 7; dx++){
                            float wv = w1s[c*49 + (wy-1)*7 + dx];
                            #pragma unroll
                            for (int t = 0; t < 8; t++) a1[1][t] = fmaf(wv, w.a[t+dx+1], a1[1][t]);
                        }
                    }
                }
                if (x0c == 56){ a1[0][7] = 0.f; a1[1][7] = 0.f; }
                #pragma unroll
                for (int rr = 0; rr < 2; rr++){
                    int r = r0 + rr;
                    if (r <= 62){
                        float4* tp = (float4*)(tc + r*68 + 4 + x0c);
                        tp[0] = make_float4(a1[rr][0],a1[rr][1],a1[rr][2],a1[rr][3]);
                        tp[1] = make_float4(a1[rr][4],a1[rr][5],a1[rr][6],a1[rr][7]);
                    }
                }
            }
            __syncthreads();
            if (act){
                #pragma unroll
                for (int wy = 0; wy < 8; wy++){
                    int ry = r0 - 3 + wy;
                    W16 w; w.v[0]=w.v[1]=w.v[2]=w.v[3] = make_float4(0.f,0.f,0.f,0.f);
                    if (ry >= 0 && ry <= 62){
                        const float4* tp = (const float4*)(tc + ry*68 + x0c);
                        w.v[0]=tp[0]; w.v[1]=tp[1]; w.v[2]=tp[2]; w.v[3]=tp[3];
                    }
                    if (wy <= 6){
                        #pragma unroll
                        for (int dx = 0; dx < 7; dx++){
                            float wv = w2s[c*49 + wy*7 + dx];
                            #pragma unroll
                            for (int t = 0; t < 8; t++) acc2[0][t] = fmaf(wv, w.a[t+dx+1], acc2[0][t]);
                        }
                    }
                    if (wy >= 1){
                        #pragma unroll
                        for (int dx = 0; dx < 7; dx++){
                            float wv = w2s[c*49 + (wy-1)*7 + dx];
                            #pragma unroll
                            for (int t = 0; t < 8; t++) acc2[1][t] = fmaf(wv, w.a[t+dx+1], acc2[1][t]);
                        }
                    }
                }
            }
            __syncthreads();
        }
        if (act){
            #pragma unroll
            for (int rr = 0; rr < 2; rr++){
                int r = r0 + rr;
                if (r <= 62){
                    float4* xp = (float4*)(xs + r*68 + x0c);
                    float4 x0v = xp[0], x1v = xp[1];
                    x0v.x += acc2[rr][0]; x0v.y += acc2[rr][1];
                    x0v.z += acc2[rr][2]; x0v.w += acc2[rr][3];
                    x1v.x += acc2[rr][4]; x1v.y += acc2[rr][5];
                    x1v.z += acc2[rr][6]; x1v.w += acc2[rr][7];
                    xp[0] = x0v; xp[1] = x1v;
                }
            }
        }
        __syncthreads();
        // ---- residual of updated x -> rP (64x64, zero pad) ----
        for (int i = tid; i < 4096; i += 1024){
            int y = i >> 6, xx = i & 63;
            float val = 0.f;
            if (y < 63 && xx < 63){
                float s = 0.f;
                #pragma unroll
                for (int dy = 0; dy < 3; dy++){
                    int u = y + dy;
                    #pragma unroll
                    for (int dx = 0; dx < 3; dx++){
                        int v = xx + dx;
                        float p;
                        if (u == 64 || v == 64)    p = 1.0f;
                        else if (u == 0 || v == 0) p = 0.0f;
                        else                       p = xs[(u-1)*68 + (v-1)];
                        s = fmaf(p, ka[dy*3 + dx], s);
                    }
                }
                val = fg[y*ND + xx] - s;
            }
            rP[i] = val;
        }
        __syncthreads();
        // ---- Phase A: T[k,c] = sum_m F[k,m] r[m,c], k=0..31 (1 row x 2 cols) --
        {
            float t0r=0.f,t0i=0.f,t1r=0.f,t1i=0.f;
            for (int m = 0; m < 63; m++){
                float fr = Frg[m*64 + kt5], fi = Fig[m*64 + kt5];  // F[k,m]=F[m,k]
                float2 rv = rP2[m*32 + ct2];
                t0r = fmaf(fr, rv.x, t0r); t0i = fmaf(fi, rv.x, t0i);
                t1r = fmaf(fr, rv.y, t1r); t1i = fmaf(fi, rv.y, t1i);
            }
            int c0 = 2*ct2;
            TtC[c0*32     + ((kt5 + c0)     & 31)] = make_float2(t0r, t0i);
            TtC[(c0+1)*32 + ((kt5 + c0 + 1) & 31)] = make_float2(t1r, t1i);
        }
        __syncthreads();
        // ---- Phase B: R = T F (rows 0..31), M = R.*v ; d-vector ----
        {
            float R0r=0.f,R0i=0.f,R1r=0.f,R1i=0.f;
            const float2* F2r = (const float2*)Frg;
            const float2* F2i = (const float2*)Fig;
            for (int n = 0; n < 63; n++){
                float2 T = TtC[n*32 + ((kt5 + n) & 31)];
                float2 fr = F2r[n*32 + ct2], fi = F2i[n*32 + ct2];
                R0r = fmaf(T.x, fr.x, R0r); R0r = fmaf(-T.y, fi.x, R0r);
                R0i = fmaf(T.x, fi.x, R0i); R0i = fmaf( T.y, fr.x, R0i);
                R1r = fmaf(T.x, fr.y, R1r); R1r = fmaf(-T.y, fi.y, R1r);
                R1i = fmaf(T.x, fi.y, R1i); R1i = fmaf( T.y, fr.y, R1i);
            }
            if (ct2 == 0){
                float2 dv = ((const float2*)dvs)[kt5];
                ds_r[kt5] = R0r*dv.x + R0i*dv.y;   // Re(conj(R)*dv)
                ds_i[kt5] = R0r*dv.y - R0i*dv.x;   // Im(conj(R)*dv)
            }
            float4 vv = ((const float4*)vcg)[(size_t)b*1024 + kt5*32 + ct2];
            float4 Mv;
            Mv.x = R0r*vv.x - R0i*vv.y;  Mv.y = R0r*vv.y + R0i*vv.x;
            Mv.z = R1r*vv.z - R1i*vv.w;  Mv.w = R1r*vv.w + R1i*vv.z;
            MC4[kt5*32 + ct2] = Mv;
        }
        __syncthreads();
        // ---- Phase D: C[n,q] = sum_l M[n,l] conj(F[l,q]), n=0..31 ----
        {
            float C0r=0.f,C0i=0.f,C1r=0.f,C1i=0.f;
            const float2* F2r = (const float2*)Frg;
            const float2* F2i = (const float2*)Fig;
            for (int l = 0; l < 63; l++){
                float2 Mv = MC2[kt5*64 + l];
                float2 fr = F2r[l*32 + ct2], fi = F2i[l*32 + ct2];
                C0r = fmaf(Mv.x, fr.x, C0r); C0r = fmaf( Mv.y, fi.x, C0r);
                C0i = fmaf(Mv.y, fr.x, C0i); C0i = fmaf(-Mv.x, fi.x, C0i);
                C1r = fmaf(Mv.x, fr.y, C1r); C1r = fmaf( Mv.y, fi.y, C1r);
                C1i = fmaf(Mv.y, fr.y, C1i); C1i = fmaf(-Mv.x, fi.y, C1i);
            }
            float scale = (kt5 == 0) ? 0.5f : 1.0f;
            CC4[kt5*33 + ct2] = make_float4(C0r*scale, C0i*scale, C1r*scale, C1i*scale);
        }
        __syncthreads();
        // ---- Phase E: y[p,q] = 2 sum_n (Fr*Cr + Fi*Ci) + e[p]; xs += y ----
        if (pE < 63){
            float yv0=0.f,yv1=0.f,yv2=0.f,yv3=0.f,e=0.f;
            for (int n = 0; n < 32; n++){
                float fr = Frg[n*64 + pE], fi = Fig[n*64 + pE];
                float4 cA = CC4[n*33 + 2*ctE];
                float4 cB = CC4[n*33 + 2*ctE + 1];
                yv0 = fmaf(fr, cA.x, yv0); yv0 = fmaf(fi, cA.y, yv0);
                yv1 = fmaf(fr, cA.z, yv1); yv1 = fmaf(fi, cA.w, yv1);
                yv2 = fmaf(fr, cB.x, yv2); yv2 = fmaf(fi, cB.y, yv2);
                yv3 = fmaf(fr, cB.z, yv3); yv3 = fmaf(fi, cB.w, yv3);
                e   = fmaf(fr, ds_r[n], e); e  = fmaf(-fi, ds_i[n], e);
            }
            float4* xp = (float4*)(xs + pE*68 + 4*ctE);
            float4 xv = *xp;
            xv.x += 2.f*yv0 + e; xv.y += 2.f*yv1 + e;
            xv.z += 2.f*yv2 + e; xv.w += 2.f*yv3 + e;
            *xp = xv;
        }
        __syncthreads();
    }
    // ---- final residual + norm ----
    float s = 0.f;
    for (int i = tid; i < NN; i += 1024){
        int y = i / ND, xx = i % ND;
        float cv = 0.f;
        #pragma unroll
        for (int dy = 0; dy < 3; dy++){
            int u = y + dy;
            #pragma unroll
            for (int dx = 0; dx < 3; dx++){
                int v = xx + dx;
                float p;
                if (u == 64 || v == 64)    p = 1.0f;
                else if (u == 0 || v == 0) p = 0.0f;
                else                       p = xs[(u-1)*68 + (v-1)];
                cv = fmaf(p, ka[dy*3 + dx], cv);
            }
        }
        float r = fg[i] - cv;
        s = fmaf(r, r, s);
    }
    #pragma unroll
    for (int off = 32; off > 0; off >>= 1) s += __shfl_down(s, off, 64);
    int lane = tid & 63, w = tid >> 6;
    if (lane == 0) red[w] = s;
    __syncthreads();
    if (tid == 0){
        float t = 0.f;
        #pragma unroll
        for (int i = 0; i < 16; i++) t += red[i];
        atomicAdd(accg, t);
    }
}

__global__ void k_final(const float* __restrict__ acc, float* __restrict__ out){
    if (threadIdx.x == 0 && blockIdx.x == 0) out[0] = sqrtf(acc[0]) * (1.0f/256.0f);
}

// ---------------- host ------------------------------------------------------
extern "C" void kernel_launch(void* const* d_in, const int* in_sizes, int n_in,
                              void* d_out, int out_size, void* d_ws, size_t ws_size,
                              hipStream_t stream){
    const float* x0     = (const float*)d_in[0];
    const float* f      = (const float*)d_in[1];
    const float* kA     = (const float*)d_in[2];
    const float* fc1_w1 = (const float*)d_in[3];
    const float* fc1_b1 = (const float*)d_in[4];
    const float* fc1_w2 = (const float*)d_in[5];
    const float* fc1_b2 = (const float*)d_in[6];
    const float* fc2_w1 = (const float*)d_in[7];
    const float* fc2_b1 = (const float*)d_in[8];
    const float* fc2_w2 = (const float*)d_in[9];
    const float* fc2_b2 = (const float*)d_in[10];
    const float* ct1_w  = (const float*)d_in[11];
    const float* ct1_b  = (const float*)d_in[12];
    const float* ct2_w  = (const float*)d_in[13];
    const float* ct2_b  = (const float*)d_in[14];
    const float* ct3_w  = (const float*)d_in[15];
    const float* ct3_b  = (const float*)d_in[16];
    const float* ct4_w  = (const float*)d_in[17];
    const float* ct4_b  = (const float*)d_in[18];
    const float* ct5_w  = (const float*)d_in[19];
    const float* ct5_b  = (const float*)d_in[20];
    float* out = (float*)d_out;

    float* ws = (float*)d_ws;
    size_t off = 0;
    auto take = [&](size_t n){ float* p = ws + off; off += (n + 63) & ~(size_t)63; return p; };
    float* Fr  = take(4096);
    float* Fi  = take(4096);
    float* acc = take(64);
    float* w1b = take((size_t)NB*147);
    float* w2b = take((size_t)NB*147);
    float* vc  = take((size_t)NB*4096);
    float* dvg = take((size_t)NB*64);
    float* c1  = take((size_t)NB*32*25);
    float* c2  = take((size_t)NB*32*81);
    float* c3  = take((size_t)NB*32*289);
    float* c4  = take((size_t)NB*32*1089);
    float* wT1 = take(288);
    float* wT2 = take(9216);
    float* wT3 = take(9216);
    float* wT4 = take(9216);
    float* wT5 = take(576);
    (void)ws_size; (void)in_sizes; (void)n_in; (void)out_size;

    k_tables<<<16, 256, 0, stream>>>(Fr, Fi, acc);
    k_wprep<<<36, 256, 0, stream>>>(ct1_w, ct2_w, ct3_w, ct4_w, ct5_w,
                                    wT1, wT2, wT3, wT4, wT5);
    k_hyper<<<NB, 192, 0, stream>>>(kA, fc1_w1, fc1_b1, fc1_w2, fc1_b2,
                                    fc2_w1, fc2_b1, fc2_w2, fc2_b2, w1b, w2b);
    k_ct1c<<<(NB*25 + 255)/256, 256, 0, stream>>>(kA, wT1, ct1_b, c1);
    k_ct32c<5> <<<NB*2, 512, 0, stream>>>(c1, wT2, ct2_b, c2);
    k_ct32c<9> <<<NB*2, 512, 0, stream>>>(c2, wT3, ct3_b, c3);
    k_ct32c<17><<<NB*2, 512, 0, stream>>>(c3, wT4, ct4_b, c4);
    k_ct5v<<<NB, 512, 0, stream>>>(c4, wT5, ct5_b, vc, dvg);
    k_solve<<<NB, 1024, 0, stream>>>(x0, f, kA, w1b, w2b, Fr, Fi, vc, dvg, acc);
    k_final<<<1, 64, 0, stream>>>(acc, out);
}